// Round 10
// baseline (208.283 us; speedup 1.0000x reference)
//
#include <hip/hip_runtime.h>
#include <hip/hip_bf16.h>

typedef __attribute__((ext_vector_type(8))) short shortx8;
typedef __attribute__((ext_vector_type(4))) float floatx4;
typedef __attribute__((ext_vector_type(4))) unsigned uintx4;
typedef __attribute__((ext_vector_type(2))) unsigned uintx2;

#define B_ 2
#define T_ 2048
#define D_ 1024
#define H_ 16
#define HD_ 64
#define SCALE 0.125f
#define SMAX 16.0f
#define FULLH ((size_t)B_ * H_ * T_ * HD_)

#define GLDS16(g, l) __builtin_amdgcn_global_load_lds( \
    (__attribute__((address_space(1))) void*)(g), \
    (__attribute__((address_space(3))) void*)(l), 16, 0, 0)

__device__ __forceinline__ short f2bf(float f) {
    union { float f; unsigned u; } v; v.f = f;
    unsigned r = v.u + 0x7FFFu + ((v.u >> 16) & 1u);
    return (short)(r >> 16);
}

__device__ __forceinline__ unsigned pk2(float x, float y) {
    union { __hip_bfloat162 h; unsigned u; } t;
    t.h = __float22bfloat162_rn(make_float2(x, y));
    return t.u;
}

__device__ __forceinline__ shortx8 cvt8(floatx4 a, floatx4 b) {
    uintx4 r = { pk2(a[0], a[1]), pk2(a[2], a[3]), pk2(b[0], b[1]), pk2(b[2], b[3]) };
    return __builtin_bit_cast(shortx8, r);
}

// ------- merged fp32->bf16 convert: x then w_qkv (q-rows pre-scaled) -------
__global__ __launch_bounds__(256) void cvt_xw(const float* __restrict__ x,
                                              const float* __restrict__ w,
                                              short* __restrict__ xbf,
                                              short* __restrict__ wbf) {
    int i = blockIdx.x * 256 + threadIdx.x;
    if (i < 524288) {
        const floatx4* p = reinterpret_cast<const floatx4*>(x) + (size_t)i * 2;
        *(reinterpret_cast<shortx8*>(xbf) + i) = cvt8(p[0], p[1]);
    } else {
        int j = i - 524288;
        const floatx4* p = reinterpret_cast<const floatx4*>(w) + (size_t)j * 2;
        floatx4 a = p[0], b = p[1];
        if (j < 131072) { a *= SCALE; b *= SCALE; }   // q rows: fold softmax scale
        *(reinterpret_cast<shortx8*>(wbf) + j) = cvt8(a, b);
    }
}

__global__ __launch_bounds__(256) void cvt_bf(const float* __restrict__ src,
                                              short* __restrict__ dst, int n8) {
    int i = blockIdx.x * 256 + threadIdx.x;
    if (i < n8) {
        const floatx4* p = reinterpret_cast<const floatx4*>(src) + (size_t)i * 2;
        *(reinterpret_cast<shortx8*>(dst) + i) = cvt8(p[0], p[1]);
    }
}

// ================= FAST GEMMs (bf16 inputs, m97-style) =================
__global__ __launch_bounds__(256) void qkv_fast(const short* __restrict__ xbf,
                                                const short* __restrict__ wbf,
                                                short* __restrict__ qout,
                                                short* __restrict__ kv) {
    __shared__ __align__(16) short As[128 * 64];
    __shared__ __align__(16) short Bs[128 * 64];

    const int tid = threadIdx.x;
    const int wv = tid >> 6;
    const int l  = tid & 63;
    const int ln = l & 15;
    const int quad = l >> 4;
    const int rowb = quad << 2;
    const int wm = wv >> 1, wn = wv & 1;
    const int m0 = blockIdx.y * 128;
    const int n0g = blockIdx.x * 128;

    const int lr = l >> 3, lc = l & 7;
    const int gcol = (lc ^ lr) << 3;
    const short* agp = xbf + (size_t)(m0 + wv * 32 + lr) * D_ + gcol;
    const short* bgp = wbf + (size_t)(n0g + wv * 32 + lr) * D_ + gcol;
    short* aldsb = As + wv * 32 * 64;
    short* bldsb = Bs + wv * 32 * 64;

    floatx4 acc[4][4] = {};

    for (int k0 = 0; k0 < D_; k0 += 64) {
        __syncthreads();
#pragma unroll
        for (int c = 0; c < 4; ++c) {
            GLDS16(agp + (size_t)(c * 8) * D_ + k0, aldsb + c * 512);
            GLDS16(bgp + (size_t)(c * 8) * D_ + k0, bldsb + c * 512);
        }
        __syncthreads();

#pragma unroll
        for (int kk = 0; kk < 2; ++kk) {
            const int csw = (kk << 2) + quad;
            const int sw = (csw ^ (ln & 7)) << 3;
            shortx8 af[4], bf[4];
#pragma unroll
            for (int i = 0; i < 4; ++i)
                af[i] = *reinterpret_cast<const shortx8*>(&As[((wm * 64 + i * 16 + ln) << 6) + sw]);
#pragma unroll
            for (int j = 0; j < 4; ++j)
                bf[j] = *reinterpret_cast<const shortx8*>(&Bs[((wn * 64 + j * 16 + ln) << 6) + sw]);
#pragma unroll
            for (int i = 0; i < 4; ++i)
#pragma unroll
                for (int j = 0; j < 4; ++j)
                    acc[i][j] = __builtin_amdgcn_mfma_f32_16x16x32_bf16(af[i], bf[j], acc[i][j], 0, 0, 0);
        }
    }

    const int sel = n0g >> 10;
    const int bb = m0 >> 11;
    const int t0w = (m0 + wm * 64) & (T_ - 1);
    const int h = ((n0g + wn * 64) >> 6) & 15;

    if (sel < 2) {
        short* dst = (sel == 0) ? qout : kv;
        const size_t hb = (size_t)(bb * H_ + h) * T_;
#pragma unroll
        for (int i = 0; i < 4; ++i)
#pragma unroll
            for (int r = 0; r < 4; ++r) {
                int t = t0w + i * 16 + rowb + r;
#pragma unroll
                for (int j = 0; j < 4; ++j)
                    dst[(hb + t) * HD_ + j * 16 + ln] = f2bf(acc[i][j][r]);
            }
    } else {
        __syncthreads();
        short* tb = (wv < 2) ? (As + wv * 4096) : (Bs + (wv - 2) * 4096);
        short* vhead = kv + FULLH + (size_t)(bb * H_ + h) * HD_ * T_;
        const int dl = l & 31, th = (l >> 5) << 5;
#pragma unroll
        for (int p = 0; p < 2; ++p) {
#pragma unroll
            for (int i = 0; i < 4; ++i)
#pragma unroll
                for (int jj = 0; jj < 2; ++jj) {
                    int j = 2 * p + jj;
#pragma unroll
                    for (int r = 0; r < 4; ++r)
                        tb[(jj * 16 + ln) * 72 + i * 16 + rowb + r] = f2bf(acc[i][j][r]);
                }
            short* vd = vhead + (size_t)(p * 32 + dl) * T_ + t0w + th;
#pragma unroll
            for (int seg = 0; seg < 4; ++seg)
                *reinterpret_cast<shortx8*>(vd + seg * 8) =
                    *reinterpret_cast<const shortx8*>(&tb[dl * 72 + th + seg * 8]);
        }
    }
}

__global__ __launch_bounds__(256) void out_fast(const short* __restrict__ Abf,
                                                const short* __restrict__ wbf,
                                                float* __restrict__ out) {
    __shared__ __align__(16) short As[128 * 64];
    __shared__ __align__(16) short Bs[128 * 64];

    const int tid = threadIdx.x;
    const int wv = tid >> 6;
    const int l  = tid & 63;
    const int ln = l & 15;
    const int quad = l >> 4;
    const int rowb = quad << 2;
    const int wm = wv >> 1, wn = wv & 1;
    const int m0 = blockIdx.y * 128;
    const int n0g = blockIdx.x * 128;

    const int lr = l >> 3, lc = l & 7;
    const int gcol = (lc ^ lr) << 3;
    const short* bgp = wbf + (size_t)(n0g + wv * 32 + lr) * D_ + gcol;
    short* aldsb = As + wv * 32 * 64;
    short* bldsb = Bs + wv * 32 * 64;

    size_t abase[4];
#pragma unroll
    for (int c = 0; c < 4; ++c) {
        int m = m0 + wv * 32 + c * 8 + lr;
        int bb2 = m >> 11, t = m & (T_ - 1);
        abase[c] = ((size_t)(bb2 * H_) * T_ + t) * HD_ + gcol;
    }

    floatx4 acc[4][4] = {};

    for (int k0 = 0; k0 < D_; k0 += 64) {
        const size_t hoff = (size_t)(k0 >> 6) * T_ * HD_;
        __syncthreads();
#pragma unroll
        for (int c = 0; c < 4; ++c) {
            GLDS16(Abf + abase[c] + hoff, aldsb + c * 512);
            GLDS16(bgp + (size_t)(c * 8) * D_ + k0, bldsb + c * 512);
        }
        __syncthreads();

#pragma unroll
        for (int kk = 0; kk < 2; ++kk) {
            const int csw = (kk << 2) + quad;
            const int sw = (csw ^ (ln & 7)) << 3;
            shortx8 af[4], bf[4];
#pragma unroll
            for (int i = 0; i < 4; ++i)
                af[i] = *reinterpret_cast<const shortx8*>(&As[((wm * 64 + i * 16 + ln) << 6) + sw]);
#pragma unroll
            for (int j = 0; j < 4; ++j)
                bf[j] = *reinterpret_cast<const shortx8*>(&Bs[((wn * 64 + j * 16 + ln) << 6) + sw]);
#pragma unroll
            for (int i = 0; i < 4; ++i)
#pragma unroll
                for (int j = 0; j < 4; ++j)
                    acc[i][j] = __builtin_amdgcn_mfma_f32_16x16x32_bf16(af[i], bf[j], acc[i][j], 0, 0, 0);
        }
    }

#pragma unroll
    for (int i = 0; i < 4; ++i)
#pragma unroll
        for (int r = 0; r < 4; ++r) {
            int m = m0 + wm * 64 + i * 16 + rowb + r;
#pragma unroll
            for (int j = 0; j < 4; ++j)
                out[(size_t)m * D_ + n0g + wn * 64 + j * 16 + ln] = acc[i][j][r];
        }
}

// ---------------- flash attention: causal-complement paired q-tiles ----------------
// grid 512: xcd=bx&7, idx=bx>>3; bh = xcd*4+(idx&3); slot = idx>>2 (0..15).
// Block handles q-tiles {slot, 31-slot}: uniform 33 tile-iterations, KV staged once.
__global__ __launch_bounds__(256, 2) void attn(const short* __restrict__ qws,
                                               const short* __restrict__ kv,
                                               short* ao) {
    __shared__ __align__(16) short Ks[64][72];
    __shared__ __align__(16) short Vt[64][72];
    __shared__ __align__(16) short Pt[4][64][20];

    const int tid = threadIdx.x;
    const int wv   = tid >> 6;
    const int l    = tid & 63;
    const int ln   = l & 15;
    const int quad = l >> 4;
    const int qd   = quad << 3;
    const int rowb = quad << 2;

    const int xcd  = blockIdx.x & 7;
    const int idx  = blockIdx.x >> 3;
    const int bh   = xcd * 4 + (idx & 3);
    const int slot = idx >> 2;               // 0..15
    const int h    = bh & 15;
    const int b    = bh >> 4;

    const float slope = exp2f(-(float)(h + 1) * (1.0f / 16.0f));
    const size_t koff = (size_t)(b * H_ + h) * T_ * HD_;

    const int qbt[2] = { slot, 31 - slot };
    int q0[2]; float base0[2];
    shortx8 qf[2][2];
#pragma unroll
    for (int qt = 0; qt < 2; ++qt) {
        q0[qt] = qbt[qt] * 64 + wv * 16;
        base0[qt] = -SMAX - slope * (float)(q0[qt] + rowb);
#pragma unroll
        for (int kk = 0; kk < 2; ++kk)
            qf[qt][kk] = *reinterpret_cast<const shortx8*>(
                &qws[koff + (size_t)(q0[qt] + ln) * HD_ + kk * 32 + qd]);
    }

    const int r0 = tid >> 3, c0 = (tid & 7) << 3, r1 = r0 + 32;
    const short* kbase = kv + koff;
    const short* vbase = kv + FULLH + koff;
    shortx8 kA, kB, vA, vB;
    auto FETCH = [&](int kb) {
        const short* kp = kbase + ((size_t)(kb * 64) << 6);
        kA = *reinterpret_cast<const shortx8*>(kp + ((size_t)r0 << 6) + c0);
        kB = *reinterpret_cast<const shortx8*>(kp + ((size_t)r1 << 6) + c0);
        const short* vp = vbase + kb * 64;
        vA = *reinterpret_cast<const shortx8*>(vp + ((size_t)r0 << 11) + c0);
        vB = *reinterpret_cast<const shortx8*>(vp + ((size_t)r1 << 11) + c0);
    };

    floatx4 oacc[2][4] = {};
    floatx4 lsum[2] = {};
    const shortx8 ones = {16256, 16256, 16256, 16256, 16256, 16256, 16256, 16256};
    const int kbmax = qbt[1];

    FETCH(0);
    for (int kb = 0; kb <= kbmax; ++kb) {
        __syncthreads();
        *reinterpret_cast<shortx8*>(&Ks[r0][c0]) = kA;
        *reinterpret_cast<shortx8*>(&Ks[r1][c0]) = kB;
        *reinterpret_cast<shortx8*>(&Vt[r0][c0]) = vA;
        *reinterpret_cast<shortx8*>(&Vt[r1][c0]) = vB;
        __syncthreads();
        if (kb < kbmax) FETCH(kb + 1);

        const int kln = kb * 64 + ln;

#pragma unroll
        for (int qt = 0; qt < 2; ++qt) {
            if (kb > qbt[qt]) continue;
            const bool diag = (kb == qbt[qt]);
            const int ncmax = diag ? (wv + 1) : 4;
            const float bb0 = slope * (float)kln + base0[qt];

#pragma unroll
            for (int nc = 0; nc < 4; ++nc) {
                floatx4 s = {};
                if (nc < ncmax) {
#pragma unroll
                    for (int kk = 0; kk < 2; ++kk) {
                        shortx8 bfr = *reinterpret_cast<const shortx8*>(&Ks[nc * 16 + ln][kk * 32 + qd]);
                        s = __builtin_amdgcn_mfma_f32_16x16x32_bf16(qf[qt][kk], bfr, s, 0, 0, 0);
                    }
                }
                float p[4];
#pragma unroll
                for (int r = 0; r < 4; ++r) {
                    bool ok = (kln + nc * 16) <= (q0[qt] + rowb + r);
                    float e = __expf(s[r] + bb0 + slope * (float)(nc * 16 - r));
                    p[r] = ok ? e : 0.0f;
                }
                uintx2 pkd = { pk2(p[0], p[1]), pk2(p[2], p[3]) };
                *reinterpret_cast<uintx2*>(&Pt[wv][nc * 16 + ln][rowb]) = pkd;
            }

#pragma unroll
            for (int kk = 0; kk < 2; ++kk) {
                if (diag && kk * 32 > wv * 16 + 15) continue;
                shortx8 pf;
#pragma unroll
                for (int j = 0; j < 8; ++j) pf[j] = Pt[wv][kk * 32 + qd + j][ln];
                lsum[qt] = __builtin_amdgcn_mfma_f32_16x16x32_bf16(pf, ones, lsum[qt], 0, 0, 0);
#pragma unroll
                for (int nc = 0; nc < 4; ++nc) {
                    shortx8 bfr = *reinterpret_cast<const shortx8*>(&Vt[nc * 16 + ln][kk * 32 + qd]);
                    oacc[qt][nc] = __builtin_amdgcn_mfma_f32_16x16x32_bf16(pf, bfr, oacc[qt][nc], 0, 0, 0);
                }
            }
        }
    }

#pragma unroll
    for (int qt = 0; qt < 2; ++qt)
#pragma unroll
        for (int r = 0; r < 4; ++r) {
            float inv = 1.0f / lsum[qt][r];
            int t = q0[qt] + rowb + r;
#pragma unroll
            for (int nc = 0; nc < 4; ++nc)
                ao[koff + (size_t)t * HD_ + nc * 16 + ln] = f2bf(oacc[qt][nc][r] * inv);
        }
}

// ================= FALLBACK PATH (fp32 inputs; Q pre-scaled here) =================
__global__ __launch_bounds__(256) void qkv_slow(const float* __restrict__ x,
                                                const float* __restrict__ wqkv,
                                                short* __restrict__ qout,
                                                short* __restrict__ kv) {
    __shared__ __align__(16) short As[64][72];
    __shared__ __align__(16) short Bs[64][72];
    const int tid = threadIdx.x;
    const int wv = tid >> 6, l = tid & 63, ln = l & 15, quad = l >> 4, qd = quad << 3;
    const int m0 = blockIdx.y * 64;
    const int sel = blockIdx.x >> 4, h = blockIdx.x & 15;
    const int nrow = sel * D_ + h * HD_;
    const int sr0 = tid >> 3, sc0 = (tid & 7) << 3, sr1 = sr0 + 32;
    floatx4 fa[4], fb[4];
    auto FETCH = [&](int k0) {
        const float* ap = &x[(size_t)(m0 + sr0) * D_ + k0 + sc0];
        fa[0] = *reinterpret_cast<const floatx4*>(ap);
        fa[1] = *reinterpret_cast<const floatx4*>(ap + 4);
        ap += (size_t)32 * D_;
        fa[2] = *reinterpret_cast<const floatx4*>(ap);
        fa[3] = *reinterpret_cast<const floatx4*>(ap + 4);
        const float* bp = &wqkv[(size_t)(nrow + sr0) * D_ + k0 + sc0];
        fb[0] = *reinterpret_cast<const floatx4*>(bp);
        fb[1] = *reinterpret_cast<const floatx4*>(bp + 4);
        bp += (size_t)32 * D_;
        fb[2] = *reinterpret_cast<const floatx4*>(bp);
        fb[3] = *reinterpret_cast<const floatx4*>(bp + 4);
    };
    floatx4 acc[4] = {};
    FETCH(0);
    for (int k0 = 0; k0 < D_; k0 += 64) {
        __syncthreads();
        *reinterpret_cast<shortx8*>(&As[sr0][sc0]) = cvt8(fa[0], fa[1]);
        *reinterpret_cast<shortx8*>(&As[sr1][sc0]) = cvt8(fa[2], fa[3]);
        *reinterpret_cast<shortx8*>(&Bs[sr0][sc0]) = cvt8(fb[0], fb[1]);
        *reinterpret_cast<shortx8*>(&Bs[sr1][sc0]) = cvt8(fb[2], fb[3]);
        __syncthreads();
        if (k0 + 64 < D_) FETCH(k0 + 64);
        const int mr = (wv << 4) + ln;
#pragma unroll
        for (int kk = 0; kk < 2; ++kk) {
            shortx8 a = *reinterpret_cast<const shortx8*>(&As[mr][kk * 32 + qd]);
#pragma unroll
            for (int nc = 0; nc < 4; ++nc) {
                shortx8 b = *reinterpret_cast<const shortx8*>(&Bs[nc * 16 + ln][kk * 32 + qd]);
                acc[nc] = __builtin_amdgcn_mfma_f32_16x16x32_bf16(a, b, acc[nc], 0, 0, 0);
            }
        }
    }
    const int bb = m0 >> 11, t0 = m0 & (T_ - 1);
    if (sel < 2) {
        short* dst = (sel == 0) ? qout : kv;
        const float sc = (sel == 0) ? SCALE : 1.0f;
#pragma unroll
        for (int r = 0; r < 4; ++r) {
            int t = t0 + (wv << 4) + (quad << 2) + r;
#pragma unroll
            for (int nc = 0; nc < 4; ++nc)
                dst[((size_t)(bb * H_ + h) * T_ + t) * HD_ + nc * 16 + ln] = f2bf(acc[nc][r] * sc);
        }
    } else {
        __syncthreads();
#pragma unroll
        for (int r = 0; r < 4; ++r)
#pragma unroll
            for (int nc = 0; nc < 4; ++nc)
                As[nc * 16 + ln][(wv << 4) + (quad << 2) + r] = f2bf(acc[nc][r]);
        __syncthreads();
        const int d = tid >> 2, tseg = (tid & 3) << 4;
        short* vdst = kv + FULLH + ((size_t)(bb * H_ + h) * HD_ + d) * T_ + t0 + tseg;
        *reinterpret_cast<shortx8*>(vdst)     = *reinterpret_cast<const shortx8*>(&As[d][tseg]);
        *reinterpret_cast<shortx8*>(vdst + 8) = *reinterpret_cast<const shortx8*>(&As[d][tseg + 8]);
    }
}

__global__ __launch_bounds__(256) void out_slow(const short* __restrict__ A,
                                                const float* __restrict__ W,
                                                float* __restrict__ out) {
    __shared__ __align__(16) short As[64][72];
    __shared__ __align__(16) short Bs[64][72];
    const int tid = threadIdx.x;
    const int wv = tid >> 6, l = tid & 63, ln = l & 15, quad = l >> 4, qd = quad << 3;
    const int m0 = blockIdx.y * 64, n0 = blockIdx.x * 64;
    const int sr0 = tid >> 3, sc0 = (tid & 7) << 3, sr1 = sr0 + 32;
    shortx8 sa0, sa1;
    floatx4 fb[4];
    auto FETCH = [&](int k0) {
        const int h = k0 >> 6;
        int m = m0 + sr0;
        int bb = m >> 11, t = m & (T_ - 1);
        sa0 = *reinterpret_cast<const shortx8*>(A + ((size_t)(bb * H_ + h) * T_ + t) * HD_ + sc0);
        m = m0 + sr1; bb = m >> 11; t = m & (T_ - 1);
        sa1 = *reinterpret_cast<const shortx8*>(A + ((size_t)(bb * H_ + h) * T_ + t) * HD_ + sc0);
        const float* bp = &W[(size_t)(n0 + sr0) * D_ + k0 + sc0];
        fb[0] = *reinterpret_cast<const floatx4*>(bp);
        fb[1] = *reinterpret_cast<const floatx4*>(bp + 4);
        bp += (size_t)32 * D_;
        fb[2] = *reinterpret_cast<const floatx4*>(bp);
        fb[3] = *reinterpret_cast<const floatx4*>(bp + 4);
    };
    floatx4 acc[4] = {};
    FETCH(0);
    for (int k0 = 0; k0 < D_; k0 += 64) {
        __syncthreads();
        *reinterpret_cast<shortx8*>(&As[sr0][sc0]) = sa0;
        *reinterpret_cast<shortx8*>(&As[sr1][sc0]) = sa1;
        *reinterpret_cast<shortx8*>(&Bs[sr0][sc0]) = cvt8(fb[0], fb[1]);
        *reinterpret_cast<shortx8*>(&Bs[sr1][sc0]) = cvt8(fb[2], fb[3]);
        __syncthreads();
        if (k0 + 64 < D_) FETCH(k0 + 64);
        const int mr = (wv << 4) + ln;
#pragma unroll
        for (int kk = 0; kk < 2; ++kk) {
            shortx8 a = *reinterpret_cast<const shortx8*>(&As[mr][kk * 32 + qd]);
#pragma unroll
            for (int nc = 0; nc < 4; ++nc) {
                shortx8 b = *reinterpret_cast<const shortx8*>(&Bs[nc * 16 + ln][kk * 32 + qd]);
                acc[nc] = __builtin_amdgcn_mfma_f32_16x16x32_bf16(a, b, acc[nc], 0, 0, 0);
            }
        }
    }
#pragma unroll
    for (int r = 0; r < 4; ++r) {
        int m = m0 + (wv << 4) + (quad << 2) + r;
#pragma unroll
        for (int nc = 0; nc < 4; ++nc)
            out[(size_t)m * D_ + n0 + nc * 16 + ln] = acc[nc][r];
    }
}

extern "C" void kernel_launch(void* const* d_in, const int* in_sizes, int n_in,
                              void* d_out, int out_size, void* d_ws, size_t ws_size,
                              hipStream_t stream) {
    const float* x    = (const float*)d_in[0];
    const float* wqkv = (const float*)d_in[1];
    const float* wout = (const float*)d_in[2];

    short* kvbuf = (short*)d_out;    // K head-major + V dim-major bf16: 16MB
    float* out   = (float*)d_out;

    if (ws_size >= 23068672ULL) {    // fast path: 22 MiB
        short* xbf  = (short*)d_ws;            // 4M shorts
        short* wbf  = xbf + 4 * 1024 * 1024;   // 3M shorts
        short* qws  = xbf + 7 * 1024 * 1024;   // 4M shorts (Q, then attn out in place)
        short* wobf = xbf;                     // overlays dead xbf after qkv_fast

        cvt_xw<<<3584, 256, 0, stream>>>(x, wqkv, xbf, wbf);
        qkv_fast<<<dim3(24, 32), 256, 0, stream>>>(xbf, wbf, qws, kvbuf);
        cvt_bf<<<512, 256, 0, stream>>>(wout, wobf, 131072);
        attn<<<dim3(512), 256, 0, stream>>>(qws, kvbuf, qws);
        out_fast<<<dim3(8, 32), 256, 0, stream>>>(qws, wobf, out);
    } else {
        short* qws = (short*)d_ws;
        qkv_slow<<<dim3(48, 64), 256, 0, stream>>>(x, wqkv, qws, kvbuf);
        attn<<<dim3(512), 256, 0, stream>>>(qws, kvbuf, qws);
        out_slow<<<dim3(16, 64), 256, 0, stream>>>(qws, wout, out);
    }
}

// Round 11
// 200.273 us; speedup vs baseline: 1.0400x; 1.0400x over previous
//
#include <hip/hip_runtime.h>
#include <hip/hip_bf16.h>

typedef __attribute__((ext_vector_type(8))) short shortx8;
typedef __attribute__((ext_vector_type(4))) float floatx4;
typedef __attribute__((ext_vector_type(4))) unsigned uintx4;
typedef __attribute__((ext_vector_type(2))) unsigned uintx2;

#define B_ 2
#define T_ 2048
#define D_ 1024
#define H_ 16
#define HD_ 64
#define SCALE 0.125f
#define SMAX 16.0f
#define FULLH ((size_t)B_ * H_ * T_ * HD_)

#define GLDS16(g, l) __builtin_amdgcn_global_load_lds( \
    (__attribute__((address_space(1))) void*)(g), \
    (__attribute__((address_space(3))) void*)(l), 16, 0, 0)

__device__ __forceinline__ short f2bf(float f) {
    union { float f; unsigned u; } v; v.f = f;
    unsigned r = v.u + 0x7FFFu + ((v.u >> 16) & 1u);
    return (short)(r >> 16);
}

__device__ __forceinline__ unsigned pk2(float x, float y) {
    union { __hip_bfloat162 h; unsigned u; } t;
    t.h = __float22bfloat162_rn(make_float2(x, y));
    return t.u;
}

__device__ __forceinline__ shortx8 cvt8(floatx4 a, floatx4 b) {
    uintx4 r = { pk2(a[0], a[1]), pk2(a[2], a[3]), pk2(b[0], b[1]), pk2(b[2], b[3]) };
    return __builtin_bit_cast(shortx8, r);
}

// ------- merged fp32->bf16 convert: x then w_qkv (q-rows pre-scaled) -------
__global__ __launch_bounds__(256) void cvt_xw(const float* __restrict__ x,
                                              const float* __restrict__ w,
                                              short* __restrict__ xbf,
                                              short* __restrict__ wbf) {
    int i = blockIdx.x * 256 + threadIdx.x;
    if (i < 524288) {
        const floatx4* p = reinterpret_cast<const floatx4*>(x) + (size_t)i * 2;
        *(reinterpret_cast<shortx8*>(xbf) + i) = cvt8(p[0], p[1]);
    } else {
        int j = i - 524288;
        const floatx4* p = reinterpret_cast<const floatx4*>(w) + (size_t)j * 2;
        floatx4 a = p[0], b = p[1];
        if (j < 131072) { a *= SCALE; b *= SCALE; }
        *(reinterpret_cast<shortx8*>(wbf) + j) = cvt8(a, b);
    }
}

__global__ __launch_bounds__(256) void cvt_bf(const float* __restrict__ src,
                                              short* __restrict__ dst, int n8) {
    int i = blockIdx.x * 256 + threadIdx.x;
    if (i < n8) {
        const floatx4* p = reinterpret_cast<const floatx4*>(src) + (size_t)i * 2;
        *(reinterpret_cast<shortx8*>(dst) + i) = cvt8(p[0], p[1]);
    }
}

// ===== FAST GEMMs: 128x128 tile, single-barrier LDS double-buffer K-loop =====
__global__ __launch_bounds__(256) void qkv_fast(const short* __restrict__ xbf,
                                                const short* __restrict__ wbf,
                                                short* __restrict__ qout,
                                                short* __restrict__ kv) {
    __shared__ __align__(16) short As[2][128 * 64];
    __shared__ __align__(16) short Bs[2][128 * 64];

    const int tid = threadIdx.x;
    const int wv = tid >> 6;
    const int l  = tid & 63;
    const int ln = l & 15;
    const int quad = l >> 4;
    const int rowb = quad << 2;
    const int wm = wv >> 1, wn = wv & 1;
    const int m0 = blockIdx.y * 128;
    const int n0g = blockIdx.x * 128;

    const int lr = l >> 3, lc = l & 7;
    const int gcol = (lc ^ lr) << 3;
    const short* agp = xbf + (size_t)(m0 + wv * 32 + lr) * D_ + gcol;
    const short* bgp = wbf + (size_t)(n0g + wv * 32 + lr) * D_ + gcol;
    const int wofs = wv * 32 * 64;

    floatx4 acc[4][4] = {};

    // stage k0=0 into buf 0
#pragma unroll
    for (int c = 0; c < 4; ++c) {
        GLDS16(agp + (size_t)(c * 8) * D_, &As[0][wofs] + c * 512);
        GLDS16(bgp + (size_t)(c * 8) * D_, &Bs[0][wofs] + c * 512);
    }
    __syncthreads();

    int cur = 0;
    for (int k0 = 0; k0 < D_; k0 += 64) {
        if (k0 + 64 < D_) {       // async-stage next into other buffer (overlaps compute)
            const int nxt = cur ^ 1;
#pragma unroll
            for (int c = 0; c < 4; ++c) {
                GLDS16(agp + (size_t)(c * 8) * D_ + k0 + 64, &As[nxt][wofs] + c * 512);
                GLDS16(bgp + (size_t)(c * 8) * D_ + k0 + 64, &Bs[nxt][wofs] + c * 512);
            }
        }
#pragma unroll
        for (int kk = 0; kk < 2; ++kk) {
            const int csw = (kk << 2) + quad;
            const int sw = (csw ^ (ln & 7)) << 3;
            shortx8 af[4], bf[4];
#pragma unroll
            for (int i = 0; i < 4; ++i)
                af[i] = *reinterpret_cast<const shortx8*>(&As[cur][((wm * 64 + i * 16 + ln) << 6) + sw]);
#pragma unroll
            for (int j = 0; j < 4; ++j)
                bf[j] = *reinterpret_cast<const shortx8*>(&Bs[cur][((wn * 64 + j * 16 + ln) << 6) + sw]);
#pragma unroll
            for (int i = 0; i < 4; ++i)
#pragma unroll
                for (int j = 0; j < 4; ++j)
                    acc[i][j] = __builtin_amdgcn_mfma_f32_16x16x32_bf16(af[i], bf[j], acc[i][j], 0, 0, 0);
        }
        __syncthreads();          // one barrier: drains nxt loads + releases cur
        cur ^= 1;
    }

    const int sel = n0g >> 10;
    const int bb = m0 >> 11;
    const int t0w = (m0 + wm * 64) & (T_ - 1);
    const int h = ((n0g + wn * 64) >> 6) & 15;

    if (sel < 2) {
        short* dst = (sel == 0) ? qout : kv;
        const size_t hb = (size_t)(bb * H_ + h) * T_;
#pragma unroll
        for (int i = 0; i < 4; ++i)
#pragma unroll
            for (int r = 0; r < 4; ++r) {
                int t = t0w + i * 16 + rowb + r;
#pragma unroll
                for (int j = 0; j < 4; ++j)
                    dst[(hb + t) * HD_ + j * 16 + ln] = f2bf(acc[i][j][r]);
            }
    } else {
        // V -> dim-major [b][h][d][t], per-wave LDS transpose scratch
        short* tb = (wv < 2) ? (&As[0][0] + wv * 4096) : (&Bs[0][0] + (wv - 2) * 4096);
        short* vhead = kv + FULLH + (size_t)(bb * H_ + h) * HD_ * T_;
        const int dl = l & 31, th = (l >> 5) << 5;
#pragma unroll
        for (int p = 0; p < 2; ++p) {
#pragma unroll
            for (int i = 0; i < 4; ++i)
#pragma unroll
                for (int jj = 0; jj < 2; ++jj) {
                    int j = 2 * p + jj;
#pragma unroll
                    for (int r = 0; r < 4; ++r)
                        tb[(jj * 16 + ln) * 72 + i * 16 + rowb + r] = f2bf(acc[i][j][r]);
                }
            __syncthreads();
            short* vd = vhead + (size_t)(p * 32 + dl) * T_ + t0w + th;
#pragma unroll
            for (int seg = 0; seg < 4; ++seg)
                *reinterpret_cast<shortx8*>(vd + seg * 8) =
                    *reinterpret_cast<const shortx8*>(&tb[dl * 72 + th + seg * 8]);
            __syncthreads();
        }
    }
}

__global__ __launch_bounds__(256) void out_fast(const short* __restrict__ Abf,
                                                const short* __restrict__ wbf,
                                                float* __restrict__ out) {
    __shared__ __align__(16) short As[2][128 * 64];
    __shared__ __align__(16) short Bs[2][128 * 64];

    const int tid = threadIdx.x;
    const int wv = tid >> 6;
    const int l  = tid & 63;
    const int ln = l & 15;
    const int quad = l >> 4;
    const int rowb = quad << 2;
    const int wm = wv >> 1, wn = wv & 1;
    const int m0 = blockIdx.y * 128;
    const int n0g = blockIdx.x * 128;

    const int lr = l >> 3, lc = l & 7;
    const int gcol = (lc ^ lr) << 3;
    const short* bgp = wbf + (size_t)(n0g + wv * 32 + lr) * D_ + gcol;
    const int wofs = wv * 32 * 64;

    size_t abase[4];
#pragma unroll
    for (int c = 0; c < 4; ++c) {
        int m = m0 + wv * 32 + c * 8 + lr;
        int bb2 = m >> 11, t = m & (T_ - 1);
        abase[c] = ((size_t)(bb2 * H_) * T_ + t) * HD_ + gcol;
    }

    floatx4 acc[4][4] = {};

#pragma unroll
    for (int c = 0; c < 4; ++c) {
        GLDS16(Abf + abase[c], &As[0][wofs] + c * 512);
        GLDS16(bgp + (size_t)(c * 8) * D_, &Bs[0][wofs] + c * 512);
    }
    __syncthreads();

    int cur = 0;
    for (int k0 = 0; k0 < D_; k0 += 64) {
        if (k0 + 64 < D_) {
            const int nxt = cur ^ 1;
            const size_t hoff = (size_t)((k0 + 64) >> 6) * T_ * HD_;
#pragma unroll
            for (int c = 0; c < 4; ++c) {
                GLDS16(Abf + abase[c] + hoff, &As[nxt][wofs] + c * 512);
                GLDS16(bgp + (size_t)(c * 8) * D_ + k0 + 64, &Bs[nxt][wofs] + c * 512);
            }
        }
#pragma unroll
        for (int kk = 0; kk < 2; ++kk) {
            const int csw = (kk << 2) + quad;
            const int sw = (csw ^ (ln & 7)) << 3;
            shortx8 af[4], bf[4];
#pragma unroll
            for (int i = 0; i < 4; ++i)
                af[i] = *reinterpret_cast<const shortx8*>(&As[cur][((wm * 64 + i * 16 + ln) << 6) + sw]);
#pragma unroll
            for (int j = 0; j < 4; ++j)
                bf[j] = *reinterpret_cast<const shortx8*>(&Bs[cur][((wn * 64 + j * 16 + ln) << 6) + sw]);
#pragma unroll
            for (int i = 0; i < 4; ++i)
#pragma unroll
                for (int j = 0; j < 4; ++j)
                    acc[i][j] = __builtin_amdgcn_mfma_f32_16x16x32_bf16(af[i], bf[j], acc[i][j], 0, 0, 0);
        }
        __syncthreads();
        cur ^= 1;
    }

#pragma unroll
    for (int i = 0; i < 4; ++i)
#pragma unroll
        for (int r = 0; r < 4; ++r) {
            int m = m0 + wm * 64 + i * 16 + rowb + r;
#pragma unroll
            for (int j = 0; j < 4; ++j)
                out[(size_t)m * D_ + n0g + wn * 64 + j * 16 + ln] = acc[i][j][r];
        }
}

// ---------------- flash attention: causal-complement paired q-tiles ----------------
__global__ __launch_bounds__(256, 2) void attn(const short* __restrict__ qws,
                                               const short* __restrict__ kv,
                                               short* ao) {
    __shared__ __align__(16) short Ks[64][72];
    __shared__ __align__(16) short Vt[64][72];
    __shared__ __align__(16) short Pt[4][64][20];

    const int tid = threadIdx.x;
    const int wv   = tid >> 6;
    const int l    = tid & 63;
    const int ln   = l & 15;
    const int quad = l >> 4;
    const int qd   = quad << 3;
    const int rowb = quad << 2;

    const int xcd  = blockIdx.x & 7;
    const int idx  = blockIdx.x >> 3;
    const int bh   = xcd * 4 + (idx & 3);
    const int slot = idx >> 2;
    const int h    = bh & 15;
    const int b    = bh >> 4;

    const float slope = exp2f(-(float)(h + 1) * (1.0f / 16.0f));
    const size_t koff = (size_t)(b * H_ + h) * T_ * HD_;

    const int qbt[2] = { slot, 31 - slot };
    int q0[2]; float base0[2];
    shortx8 qf[2][2];
#pragma unroll
    for (int qt = 0; qt < 2; ++qt) {
        q0[qt] = qbt[qt] * 64 + wv * 16;
        base0[qt] = -SMAX - slope * (float)(q0[qt] + rowb);
#pragma unroll
        for (int kk = 0; kk < 2; ++kk)
            qf[qt][kk] = *reinterpret_cast<const shortx8*>(
                &qws[koff + (size_t)(q0[qt] + ln) * HD_ + kk * 32 + qd]);
    }

    const int r0 = tid >> 3, c0 = (tid & 7) << 3, r1 = r0 + 32;
    const short* kbase = kv + koff;
    const short* vbase = kv + FULLH + koff;
    shortx8 kA, kB, vA, vB;
    auto FETCH = [&](int kb) {
        const short* kp = kbase + ((size_t)(kb * 64) << 6);
        kA = *reinterpret_cast<const shortx8*>(kp + ((size_t)r0 << 6) + c0);
        kB = *reinterpret_cast<const shortx8*>(kp + ((size_t)r1 << 6) + c0);
        const short* vp = vbase + kb * 64;
        vA = *reinterpret_cast<const shortx8*>(vp + ((size_t)r0 << 11) + c0);
        vB = *reinterpret_cast<const shortx8*>(vp + ((size_t)r1 << 11) + c0);
    };

    floatx4 oacc[2][4] = {};
    floatx4 lsum[2] = {};
    const shortx8 ones = {16256, 16256, 16256, 16256, 16256, 16256, 16256, 16256};
    const int kbmax = qbt[1];

    FETCH(0);
    for (int kb = 0; kb <= kbmax; ++kb) {
        __syncthreads();
        *reinterpret_cast<shortx8*>(&Ks[r0][c0]) = kA;
        *reinterpret_cast<shortx8*>(&Ks[r1][c0]) = kB;
        *reinterpret_cast<shortx8*>(&Vt[r0][c0]) = vA;
        *reinterpret_cast<shortx8*>(&Vt[r1][c0]) = vB;
        __syncthreads();
        if (kb < kbmax) FETCH(kb + 1);

        const int kln = kb * 64 + ln;

#pragma unroll
        for (int qt = 0; qt < 2; ++qt) {
            if (kb > qbt[qt]) continue;
            const bool diag = (kb == qbt[qt]);
            const int ncmax = diag ? (wv + 1) : 4;
            const float bb0 = slope * (float)kln + base0[qt];

#pragma unroll
            for (int nc = 0; nc < 4; ++nc) {
                floatx4 s = {};
                if (nc < ncmax) {
#pragma unroll
                    for (int kk = 0; kk < 2; ++kk) {
                        shortx8 bfr = *reinterpret_cast<const shortx8*>(&Ks[nc * 16 + ln][kk * 32 + qd]);
                        s = __builtin_amdgcn_mfma_f32_16x16x32_bf16(qf[qt][kk], bfr, s, 0, 0, 0);
                    }
                }
                float p[4];
#pragma unroll
                for (int r = 0; r < 4; ++r) {
                    bool ok = (kln + nc * 16) <= (q0[qt] + rowb + r);
                    float e = __expf(s[r] + bb0 + slope * (float)(nc * 16 - r));
                    p[r] = ok ? e : 0.0f;
                }
                uintx2 pkd = { pk2(p[0], p[1]), pk2(p[2], p[3]) };
                *reinterpret_cast<uintx2*>(&Pt[wv][nc * 16 + ln][rowb]) = pkd;
            }

#pragma unroll
            for (int kk = 0; kk < 2; ++kk) {
                if (diag && kk * 32 > wv * 16 + 15) continue;
                shortx8 pf;
#pragma unroll
                for (int j = 0; j < 8; ++j) pf[j] = Pt[wv][kk * 32 + qd + j][ln];
                lsum[qt] = __builtin_amdgcn_mfma_f32_16x16x32_bf16(pf, ones, lsum[qt], 0, 0, 0);
#pragma unroll
                for (int nc = 0; nc < 4; ++nc) {
                    shortx8 bfr = *reinterpret_cast<const shortx8*>(&Vt[nc * 16 + ln][kk * 32 + qd]);
                    oacc[qt][nc] = __builtin_amdgcn_mfma_f32_16x16x32_bf16(pf, bfr, oacc[qt][nc], 0, 0, 0);
                }
            }
        }
    }

#pragma unroll
    for (int qt = 0; qt < 2; ++qt)
#pragma unroll
        for (int r = 0; r < 4; ++r) {
            float inv = 1.0f / lsum[qt][r];
            int t = q0[qt] + rowb + r;
#pragma unroll
            for (int nc = 0; nc < 4; ++nc)
                ao[koff + (size_t)t * HD_ + nc * 16 + ln] = f2bf(oacc[qt][nc][r] * inv);
        }
}

// ================= FALLBACK PATH (fp32 inputs) =================
__global__ __launch_bounds__(256) void qkv_slow(const float* __restrict__ x,
                                                const float* __restrict__ wqkv,
                                                short* __restrict__ qout,
                                                short* __restrict__ kv) {
    __shared__ __align__(16) short As[64][72];
    __shared__ __align__(16) short Bs[64][72];
    const int tid = threadIdx.x;
    const int wv = tid >> 6, l = tid & 63, ln = l & 15, quad = l >> 4, qd = quad << 3;
    const int m0 = blockIdx.y * 64;
    const int sel = blockIdx.x >> 4, h = blockIdx.x & 15;
    const int nrow = sel * D_ + h * HD_;
    const int sr0 = tid >> 3, sc0 = (tid & 7) << 3, sr1 = sr0 + 32;
    floatx4 fa[4], fb[4];
    auto FETCH = [&](int k0) {
        const float* ap = &x[(size_t)(m0 + sr0) * D_ + k0 + sc0];
        fa[0] = *reinterpret_cast<const floatx4*>(ap);
        fa[1] = *reinterpret_cast<const floatx4*>(ap + 4);
        ap += (size_t)32 * D_;
        fa[2] = *reinterpret_cast<const floatx4*>(ap);
        fa[3] = *reinterpret_cast<const floatx4*>(ap + 4);
        const float* bp = &wqkv[(size_t)(nrow + sr0) * D_ + k0 + sc0];
        fb[0] = *reinterpret_cast<const floatx4*>(bp);
        fb[1] = *reinterpret_cast<const floatx4*>(bp + 4);
        bp += (size_t)32 * D_;
        fb[2] = *reinterpret_cast<const floatx4*>(bp);
        fb[3] = *reinterpret_cast<const floatx4*>(bp + 4);
    };
    floatx4 acc[4] = {};
    FETCH(0);
    for (int k0 = 0; k0 < D_; k0 += 64) {
        __syncthreads();
        *reinterpret_cast<shortx8*>(&As[sr0][sc0]) = cvt8(fa[0], fa[1]);
        *reinterpret_cast<shortx8*>(&As[sr1][sc0]) = cvt8(fa[2], fa[3]);
        *reinterpret_cast<shortx8*>(&Bs[sr0][sc0]) = cvt8(fb[0], fb[1]);
        *reinterpret_cast<shortx8*>(&Bs[sr1][sc0]) = cvt8(fb[2], fb[3]);
        __syncthreads();
        if (k0 + 64 < D_) FETCH(k0 + 64);
        const int mr = (wv << 4) + ln;
#pragma unroll
        for (int kk = 0; kk < 2; ++kk) {
            shortx8 a = *reinterpret_cast<const shortx8*>(&As[mr][kk * 32 + qd]);
#pragma unroll
            for (int nc = 0; nc < 4; ++nc) {
                shortx8 b = *reinterpret_cast<const shortx8*>(&Bs[nc * 16 + ln][kk * 32 + qd]);
                acc[nc] = __builtin_amdgcn_mfma_f32_16x16x32_bf16(a, b, acc[nc], 0, 0, 0);
            }
        }
    }
    const int bb = m0 >> 11, t0 = m0 & (T_ - 1);
    if (sel < 2) {
        short* dst = (sel == 0) ? qout : kv;
        const float sc = (sel == 0) ? SCALE : 1.0f;
#pragma unroll
        for (int r = 0; r < 4; ++r) {
            int t = t0 + (wv << 4) + (quad << 2) + r;
#pragma unroll
            for (int nc = 0; nc < 4; ++nc)
                dst[((size_t)(bb * H_ + h) * T_ + t) * HD_ + nc * 16 + ln] = f2bf(acc[nc][r] * sc);
        }
    } else {
        __syncthreads();
#pragma unroll
        for (int r = 0; r < 4; ++r)
#pragma unroll
            for (int nc = 0; nc < 4; ++nc)
                As[nc * 16 + ln][(wv << 4) + (quad << 2) + r] = f2bf(acc[nc][r]);
        __syncthreads();
        const int d = tid >> 2, tseg = (tid & 3) << 4;
        short* vdst = kv + FULLH + ((size_t)(bb * H_ + h) * HD_ + d) * T_ + t0 + tseg;
        *reinterpret_cast<shortx8*>(vdst)     = *reinterpret_cast<const shortx8*>(&As[d][tseg]);
        *reinterpret_cast<shortx8*>(vdst + 8) = *reinterpret_cast<const shortx8*>(&As[d][tseg + 8]);
    }
}

__global__ __launch_bounds__(256) void out_slow(const short* __restrict__ A,
                                                const float* __restrict__ W,
                                                float* __restrict__ out) {
    __shared__ __align__(16) short As[64][72];
    __shared__ __align__(16) short Bs[64][72];
    const int tid = threadIdx.x;
    const int wv = tid >> 6, l = tid & 63, ln = l & 15, quad = l >> 4, qd = quad << 3;
    const int m0 = blockIdx.y * 64, n0 = blockIdx.x * 64;
    const int sr0 = tid >> 3, sc0 = (tid & 7) << 3, sr1 = sr0 + 32;
    shortx8 sa0, sa1;
    floatx4 fb[4];
    auto FETCH = [&](int k0) {
        const int h = k0 >> 6;
        int m = m0 + sr0;
        int bb = m >> 11, t = m & (T_ - 1);
        sa0 = *reinterpret_cast<const shortx8*>(A + ((size_t)(bb * H_ + h) * T_ + t) * HD_ + sc0);
        m = m0 + sr1; bb = m >> 11; t = m & (T_ - 1);
        sa1 = *reinterpret_cast<const shortx8*>(A + ((size_t)(bb * H_ + h) * T_ + t) * HD_ + sc0);
        const float* bp = &W[(size_t)(n0 + sr0) * D_ + k0 + sc0];
        fb[0] = *reinterpret_cast<const floatx4*>(bp);
        fb[1] = *reinterpret_cast<const floatx4*>(bp + 4);
        bp += (size_t)32 * D_;
        fb[2] = *reinterpret_cast<const floatx4*>(bp);
        fb[3] = *reinterpret_cast<const floatx4*>(bp + 4);
    };
    floatx4 acc[4] = {};
    FETCH(0);
    for (int k0 = 0; k0 < D_; k0 += 64) {
        __syncthreads();
        *reinterpret_cast<shortx8*>(&As[sr0][sc0]) = sa0;
        *reinterpret_cast<shortx8*>(&As[sr1][sc0]) = sa1;
        *reinterpret_cast<shortx8*>(&Bs[sr0][sc0]) = cvt8(fb[0], fb[1]);
        *reinterpret_cast<shortx8*>(&Bs[sr1][sc0]) = cvt8(fb[2], fb[3]);
        __syncthreads();
        if (k0 + 64 < D_) FETCH(k0 + 64);
        const int mr = (wv << 4) + ln;
#pragma unroll
        for (int kk = 0; kk < 2; ++kk) {
            shortx8 a = *reinterpret_cast<const shortx8*>(&As[mr][kk * 32 + qd]);
#pragma unroll
            for (int nc = 0; nc < 4; ++nc) {
                shortx8 b = *reinterpret_cast<const shortx8*>(&Bs[nc * 16 + ln][kk * 32 + qd]);
                acc[nc] = __builtin_amdgcn_mfma_f32_16x16x32_bf16(a, b, acc[nc], 0, 0, 0);
            }
        }
    }
#pragma unroll
    for (int r = 0; r < 4; ++r) {
        int m = m0 + (wv << 4) + (quad << 2) + r;
#pragma unroll
        for (int nc = 0; nc < 4; ++nc)
            out[(size_t)m * D_ + n0 + nc * 16 + ln] = acc[nc][r];
    }
}

extern "C" void kernel_launch(void* const* d_in, const int* in_sizes, int n_in,
                              void* d_out, int out_size, void* d_ws, size_t ws_size,
                              hipStream_t stream) {
    const float* x    = (const float*)d_in[0];
    const float* wqkv = (const float*)d_in[1];
    const float* wout = (const float*)d_in[2];

    short* kvbuf = (short*)d_out;
    float* out   = (float*)d_out;

    if (ws_size >= 23068672ULL) {
        short* xbf  = (short*)d_ws;
        short* wbf  = xbf + 4 * 1024 * 1024;
        short* qws  = xbf + 7 * 1024 * 1024;
        short* wobf = xbf;

        cvt_xw<<<3584, 256, 0, stream>>>(x, wqkv, xbf, wbf);
        qkv_fast<<<dim3(24, 32), 256, 0, stream>>>(xbf, wbf, qws, kvbuf);
        cvt_bf<<<512, 256, 0, stream>>>(wout, wobf, 131072);
        attn<<<dim3(512), 256, 0, stream>>>(qws, kvbuf, qws);
        out_fast<<<dim3(8, 32), 256, 0, stream>>>(qws, wobf, out);
    } else {
        short* qws = (short*)d_ws;
        qkv_slow<<<dim3(48, 64), 256, 0, stream>>>(x, wqkv, qws, kvbuf);
        attn<<<dim3(512), 256, 0, stream>>>(qws, kvbuf, qws);
        out_slow<<<dim3(16, 64), 256, 0, stream>>>(qws, wout, out);
    }
}